// Round 4
// baseline (212.174 us; speedup 1.0000x reference)
//
#include <hip/hip_runtime.h>

#define NGRAPH 256
#define NN     128   // nodes per graph
#define NT     16    // templates
#define NM     10    // template nodes
#define OUTER_IT 5
#define SINK_IT  20

// K = exp(-20*tens) = exp2(-20*log2(e)*tens)
#define SC1  28.85390081777927f    // 20*log2(e)
#define SC2  57.70780163555854f    // 40*log2(e)

// P row stride (floats): 48B, 16B-aligned -> b128 gather ops. Round-1 lesson:
// gather rows are RANDOM neighbor indices; conflicts are multinomial imbalance
// no stride fixes; wide b128 minimizes LDS instruction count (stride-14/b64
// was strictly worse: conflicts 8.3M -> 12.8M, dur 148 -> 179).
#define PSTR 12

typedef unsigned long long u64;
typedef float v2f __attribute__((ext_vector_type(2)));
typedef float v4f __attribute__((ext_vector_type(4)));

static __device__ __forceinline__ v2f pkfma(v2f a, v2f b, v2f c) {
  return __builtin_elementwise_fma(a, b, c);
}
static __device__ __forceinline__ v2f bc2(float s) { return (v2f){s, s}; }

// DPP xor-butterfly add within a 16-lane row (masks {1,2,7,15} span (Z2)^4).
template <int CTRL>
__device__ __forceinline__ float dpp_add(float a) {
  int t = __builtin_amdgcn_update_dpp(0, __float_as_int(a), CTRL, 0xf, 0xf, true);
  return a + __int_as_float(t);
}

// xor-16 exchange+add via gfx950 v_permlane16_swap_b32: pure VALU, replaces
// ds_swizzle (LDS pipe, ~120cy, ~1000 on the Sinkhorn critical path).
// Verified bit-exact on harness in rounds 0-1.
#if defined(__has_builtin)
#if __has_builtin(__builtin_amdgcn_permlane16_swap)
#define HAVE_PL16SWAP 1
#endif
#endif
__device__ __forceinline__ float xor16_add(float x) {
#ifdef HAVE_PL16SWAP
  auto rr = __builtin_amdgcn_permlane16_swap(__float_as_int(x), __float_as_int(x),
                                             false, false);
  return __int_as_float((int)rr[0]) + __int_as_float((int)rr[1]);
#else
  float a = x, b = x, r;
  asm("s_nop 1\n\t"
      "v_permlane16_swap_b32 %1, %2\n\t"
      "s_nop 1\n\t"
      "v_add_f32 %0, %1, %2"
      : "=v"(r), "+v"(a), "+v"(b));
  return r;
#endif
}

// Sum over each 32-lane group; result broadcast to all lanes of the group.
__device__ __forceinline__ float allsum32(float x) {
  x = dpp_add<0xB1>(x);    // quad_perm xor 1
  x = dpp_add<0x4E>(x);    // quad_perm xor 2
  x = dpp_add<0x141>(x);   // row_half_mirror: xor 7
  x = dpp_add<0x140>(x);   // row_mirror: xor 15
  return xor16_add(x);     // xor 16 (VALU, no LDS pipe)
}

// 32 lanes per (graph b, template t) pair, 2 pairs per 64-thread single-wave
// block (empirically the best decomposition: 2 waves/SIMD, moderate per-pair
// work). Lane owns 4 rows r = sub + 32*c. P: LDS fp32, stride 12, b128 ops.
__global__ __launch_bounds__(64, 2)
void tgw_kernel(const int* __restrict__ ei,
                const float* __restrict__ tadj,
                const float* __restrict__ q0g,
                float* __restrict__ out,
                int E, int ne) {
  const int lane = threadIdx.x;
  const int p    = lane >> 5;        // pair slot 0/1
  const int sub  = lane & 31;
  const int b    = blockIdx.x >> 3;
  const int t0   = (blockIdx.x & 7) * 2;   // templates t0, t0+1

  __shared__ __align__(16) unsigned adj[NN][4];    // 2 KB
  __shared__ __align__(16) float Pls[2][NN][PSTR]; // 12 KB
  __shared__ __align__(16) v2f C2T[2][NM][6];      // SC2*C2, [m][jpair]
  __shared__ float q0s[2][NM];

  // ---- stage ----
  for (int i = lane; i < NN * 4; i += 64) (&adj[0][0])[i] = 0u;
  // C2T[tt][m][jp] = SC2 * { C2[2jp][m], C2[2jp+1][m] }  (transposed pairs)
  for (int i = lane; i < 2 * NM * 5; i += 64) {
    int tt = i / 50, r = i % 50, m = r / 5, jp = r % 5;
    const float* bp = tadj + (t0 + tt) * NM * NM + m;
    C2T[tt][m][jp] = (v2f){bp[(2 * jp) * NM], bp[(2 * jp + 1) * NM]} * SC2;
  }
  if (lane < 2 * NM) q0s[lane / NM][lane % NM] = q0g[t0 * NM + lane];
  __syncthreads();

  // symmetric 0/1 adjacency from the edge list (dups/self-loops harmless)
  const int* srcp = ei;
  const int* dstp = ei + E;
  const int ebase = b * ne;
  for (int e = lane; e < ne; e += 64) {
    int s = srcp[ebase + e] & (NN - 1);
    int d = dstp[ebase + e] & (NN - 1);
    atomicOr(&adj[s][d >> 5], 1u << (d & 31));
    atomicOr(&adj[d][s >> 5], 1u << (s & 31));
  }
  __syncthreads();

  // ---- per-pair constants ----
  float qv[NM];
  {
    float mx = q0s[p][0];
    #pragma unroll
    for (int j = 1; j < NM; ++j) mx = fmaxf(mx, q0s[p][j]);
    float s = 0.f;
    #pragma unroll
    for (int j = 0; j < NM; ++j) { qv[j] = __expf(q0s[p][j] - mx); s += qv[j]; }
    float inv = __builtin_amdgcn_rcpf(s);
    #pragma unroll
    for (int j = 0; j < NM; ++j) qv[j] *= inv;
  }
  // q2d = q*128: pw=1/128 folded out of the Sinkhorn inner loop
  // (u' = rcp(rowsum)). Exact power-of-2 scalings -> identical values.
  // Verified bit-exact on harness in rounds 1-2.
  v2f q2d[5];
  #pragma unroll
  for (int jp = 0; jp < 5; ++jp)
    q2d[jp] = (v2f){qv[2 * jp] * 128.f, qv[2 * jp + 1] * 128.f};

  // fq2[jp] = -SC1 * f2q[jpair]; f2q[j] = sum_m C2[j][m]^2 q[m]
  // C2 = C2T/SC2 => factor -SC1/SC2^2 = -1/(4*SC1)
  // qC2T[jp] = sum_m q[m] * C2T[m][jp]   (for the o==0 analytic cost)
  v2f fq2[5], qC2T[5];
  {
    #pragma unroll
    for (int jp = 0; jp < 5; ++jp) { fq2[jp] = (v2f){0.f, 0.f}; qC2T[jp] = (v2f){0.f, 0.f}; }
    #pragma unroll
    for (int m = 0; m < NM; ++m) {
      v2f qb = bc2(qv[m]);
      #pragma unroll
      for (int jp = 0; jp < 5; ++jp) {
        v2f c = C2T[p][m][jp];
        fq2[jp]  = pkfma(c * c, qb, fq2[jp]);
        qC2T[jp] = pkfma(c, qb, qC2T[jp]);
      }
    }
    const float f = -1.0f / (4.0f * SC1);
    #pragma unroll
    for (int jp = 0; jp < 5; ++jp) fq2[jp] *= f;
  }

  const float pw = 1.0f / 128.0f;
  float f1p[4], m1f1[4];
  #pragma unroll
  for (int c = 0; c < 4; ++c) {
    uint4 mm = *(const uint4*)&adj[sub + 32 * c][0];
    u64 m0 = mm.x | ((u64)mm.y << 32), m1 = mm.z | ((u64)mm.w << 32);
    f1p[c]  = (float)(__popcll(m0) + __popcll(m1)) * pw;   // C1*C1 == C1
    m1f1[c] = -SC1 * f1p[c];
  }

  const float* Pbase = &Pls[p][0][0];

  // Accumulate one neighbor row (b128+b128+b64) into S.
  auto accRow = [&](int k, v2f* S) {
    const float* row = Pbase + k * PSTR;
    v4f A = *(const v4f*)row;
    v4f B = *(const v4f*)(row + 4);
    v2f C = *(const v2f*)(row + 8);
    S[0] += A.xy; S[1] += A.zw; S[2] += B.xy; S[3] += B.zw; S[4] += C;
  };

  // S = (C1 @ P) for TWO rows jointly: the paired walk keeps 6 wide loads in
  // flight (vs 3 in the serial per-row walk), halving exposed LDS latency in
  // the dominant stall phase. Per-row add order stays ascending-k (m0 bits
  // then m1 bits) -> sums bitwise identical to the serial walk.
  auto gather2 = [&](int ra, int rb, v2f* SA, v2f* SB) {
    uint4 ma = *(const uint4*)&adj[ra][0];
    uint4 mb = *(const uint4*)&adj[rb][0];
    u64 a0 = ma.x | ((u64)ma.y << 32), a1 = ma.z | ((u64)ma.w << 32);
    u64 b0 = mb.x | ((u64)mb.y << 32), b1 = mb.z | ((u64)mb.w << 32);
    #pragma unroll
    for (int h = 0; h < 5; ++h) { SA[h] = (v2f){0.f, 0.f}; SB[h] = (v2f){0.f, 0.f}; }
    while (a0 && b0) {
      int ka = (int)__builtin_ctzll(a0); a0 &= a0 - 1;
      int kb = (int)__builtin_ctzll(b0); b0 &= b0 - 1;
      accRow(ka, SA);
      accRow(kb, SB);
    }
    while (a0) { int k = (int)__builtin_ctzll(a0); a0 &= a0 - 1; accRow(k, SA); }
    while (b0) { int k = (int)__builtin_ctzll(b0); b0 &= b0 - 1; accRow(k, SB); }
    while (a1 && b1) {
      int ka = 64 + (int)__builtin_ctzll(a1); a1 &= a1 - 1;
      int kb = 64 + (int)__builtin_ctzll(b1); b1 &= b1 - 1;
      accRow(ka, SA);
      accRow(kb, SB);
    }
    while (a1) { int k = 64 + (int)__builtin_ctzll(a1); a1 &= a1 - 1; accRow(k, SA); }
    while (b1) { int k = 64 + (int)__builtin_ctzll(b1); b1 &= b1 - 1; accRow(k, SB); }
  };

  // Gather all 4 lane rows (two joint walks), unpack to scalar S.
  auto gather4 = [&](float Sm[4][NM]) {
    v2f S2[4][5];
    gather2(sub + 32 * 0, sub + 32 * 1, S2[0], S2[1]);
    gather2(sub + 32 * 2, sub + 32 * 3, S2[2], S2[3]);
    #pragma unroll
    for (int c = 0; c < 4; ++c)
      #pragma unroll
      for (int h = 0; h < 5; ++h) { Sm[c][2 * h] = S2[c][h].x; Sm[c][2 * h + 1] = S2[c][h].y; }
  };

  // arg2[c][jp] = -SC1*tens (packed over jpairs), from scalar S[m] per row
  auto costFromS = [&](float Sm[4][NM], v2f arg2[4][5]) {
    #pragma unroll
    for (int c = 0; c < 4; ++c) {
      #pragma unroll
      for (int jp = 0; jp < 5; ++jp) arg2[c][jp] = fq2[jp] + bc2(m1f1[c]);
    }
    #pragma unroll
    for (int m = 0; m < NM; ++m) {
      v4f X = *(const v4f*)&C2T[p][m][0];   // jp 0,1
      v4f Y = *(const v4f*)&C2T[p][m][2];   // jp 2,3
      v2f Z = *(const v2f*)&C2T[p][m][4];   // jp 4
      #pragma unroll
      for (int c = 0; c < 4; ++c) {
        v2f sb = bc2(Sm[c][m]);
        arg2[c][0] = pkfma(sb, X.xy, arg2[c][0]);
        arg2[c][1] = pkfma(sb, X.zw, arg2[c][1]);
        arg2[c][2] = pkfma(sb, Y.xy, arg2[c][2]);
        arg2[c][3] = pkfma(sb, Y.zw, arg2[c][3]);
        arg2[c][4] = pkfma(sb, Z,    arg2[c][4]);
      }
    }
  };

  v2f K2[4][5], v2[5], arg2[4][5];
  float uu[4];

  for (int o = 0; o < OUTER_IT; ++o) {
    // ---- cost -> arg2 -> K = exp2(arg) ----
    if (o == 0) {
      // P0 = p q^T => S[c][m] = f1p[c]*q[m] => sum_m S C2T = f1p[c]*qC2T
      #pragma unroll
      for (int c = 0; c < 4; ++c) {
        v2f fb = bc2(f1p[c]);
        v2f ob = bc2(m1f1[c]);
        #pragma unroll
        for (int jp = 0; jp < 5; ++jp)
          arg2[c][jp] = pkfma(fb, qC2T[jp], fq2[jp] + ob);
      }
    } else {
      float Sm[4][NM];
      gather4(Sm);
      costFromS(Sm, arg2);
    }
    #pragma unroll
    for (int c = 0; c < 4; ++c)
      #pragma unroll
      for (int jp = 0; jp < 5; ++jp)
        K2[c][jp] = (v2f){exp2f(arg2[c][jp].x), exp2f(arg2[c][jp].y)};

    // ---- Sinkhorn (v starts at ones; pw folded: uu = rcp(rowsum)) ----
    #pragma unroll
    for (int jp = 0; jp < 5; ++jp) v2[jp] = (v2f){1.f, 1.f};
    for (int it = 0; it < SINK_IT; ++it) {
      #pragma unroll
      for (int c = 0; c < 4; ++c) {
        v2f d2 = K2[c][0] * v2[0];
        d2 = pkfma(K2[c][1], v2[1], d2);
        d2 = pkfma(K2[c][2], v2[2], d2);
        d2 = pkfma(K2[c][3], v2[3], d2);
        d2 = pkfma(K2[c][4], v2[4], d2);
        uu[c] = __builtin_amdgcn_rcpf(d2.x + d2.y);
      }
      #pragma unroll
      for (int jp = 0; jp < 5; ++jp) {
        v2f w2 = K2[0][jp] * bc2(uu[0]);
        w2 = pkfma(K2[1][jp], bc2(uu[1]), w2);
        w2 = pkfma(K2[2][jp], bc2(uu[2]), w2);
        w2 = pkfma(K2[3][jp], bc2(uu[3]), w2);
        float cx = allsum32(w2.x);
        float cy = allsum32(w2.y);
        v2[jp] = (v2f){q2d[jp].x * __builtin_amdgcn_rcpf(cx),
                       q2d[jp].y * __builtin_amdgcn_rcpf(cy)};
      }
    }

    // ---- P = diag(u) K diag(v) -> LDS (re-apply pw once here) ----
    __syncthreads();   // single-wave block: just drains LDS ops, ~free
    #pragma unroll
    for (int c = 0; c < 4; ++c) {
      v2f ub = bc2(uu[c] * pw);   // exact *2^-7
      v2f x0 = K2[c][0] * ub * v2[0];
      v2f x1 = K2[c][1] * ub * v2[1];
      v2f x2 = K2[c][2] * ub * v2[2];
      v2f x3 = K2[c][3] * ub * v2[3];
      v2f x4 = K2[c][4] * ub * v2[4];
      float* row = &Pls[p][sub + 32 * c][0];
      *(v4f*)row       = (v4f){x0.x, x0.y, x1.x, x1.y};
      *(v4f*)(row + 4) = (v4f){x2.x, x2.y, x3.x, x3.y};
      *(v2f*)(row + 8) = x4;
    }
    __syncthreads();
  }

  // ---- GW = sum_ij tens(P)_ij * P_ij,  tens = arg * (-1/SC1) ----
  float acc = 0.f;
  {
    float Sm[4][NM];
    gather4(Sm);
    costFromS(Sm, arg2);
    const v2f nf = bc2(-1.0f / SC1);
    v2f acc2 = (v2f){0.f, 0.f};
    #pragma unroll
    for (int c = 0; c < 4; ++c) {
      v2f ub = bc2(uu[c] * pw);
      #pragma unroll
      for (int jp = 0; jp < 5; ++jp) {
        v2f Pv = K2[c][jp] * ub * v2[jp];
        acc2 = pkfma(arg2[c][jp] * nf, Pv, acc2);
      }
    }
    acc = acc2.x + acc2.y;
  }
  float total = allsum32(acc);
  if (sub == 0) out[b * NT + t0 + p] = total;
}

extern "C" void kernel_launch(void* const* d_in, const int* in_sizes, int n_in,
                              void* d_out, int out_size, void* d_ws, size_t ws_size,
                              hipStream_t stream) {
  // inputs: 0 x(f32, unused) 1 edge_index(int32) 2 batch(int32, unused)
  //         3 tplt_adjacencies(f32) 4 tplt_features(f32, unused) 5 q0(f32)
  const int* ei   = (const int*)d_in[1];
  const float* c2 = (const float*)d_in[3];
  const float* q0 = (const float*)d_in[5];
  float* out      = (float*)d_out;
  const int E  = in_sizes[1] / 2;
  const int ne = E / NGRAPH;
  tgw_kernel<<<dim3(NGRAPH * 8), dim3(64), 0, stream>>>(ei, c2, q0, out, E, ne);
}

// Round 5
// 211.953 us; speedup vs baseline: 1.0010x; 1.0010x over previous
//
#include <hip/hip_runtime.h>

#define NGRAPH 256
#define NN     128   // nodes per graph
#define NT     16    // templates
#define NM     10    // template nodes
#define OUTER_IT 5
#define SINK_IT  20

// K = exp(-20*tens) = exp2(-20*log2(e)*tens)
#define SC1  28.85390081777927f    // 20*log2(e)
#define SC2  57.70780163555854f    // 40*log2(e)

// P row stride (floats): 48B, 16B-aligned -> b128 gather ops. Round-1 lesson:
// gather rows are RANDOM neighbor indices; conflicts are multinomial imbalance
// no stride fixes; wide b128 minimizes LDS instruction count.
#define PSTR 12

typedef unsigned long long u64;
typedef float v2f __attribute__((ext_vector_type(2)));
typedef float v4f __attribute__((ext_vector_type(4)));

static __device__ __forceinline__ v2f pkfma(v2f a, v2f b, v2f c) {
  return __builtin_elementwise_fma(a, b, c);
}
static __device__ __forceinline__ v2f bc2(float s) { return (v2f){s, s}; }

// DPP xor-butterfly add within a 16-lane row (masks {1,2,7,15} span (Z2)^4).
template <int CTRL>
__device__ __forceinline__ float dpp_add(float a) {
  int t = __builtin_amdgcn_update_dpp(0, __float_as_int(a), CTRL, 0xf, 0xf, true);
  return a + __int_as_float(t);
}

// xor-16 exchange+add via gfx950 v_permlane16_swap_b32: pure VALU, replaces
// ds_swizzle (LDS pipe, ~120cy on the serial u<->v Sinkhorn chain, ~1000
// instances per wave). Harness-verified in rounds 0/1/3.
#if defined(__has_builtin)
#if __has_builtin(__builtin_amdgcn_permlane16_swap)
#define HAVE_PL16SWAP 1
#endif
#endif
__device__ __forceinline__ float xor16_add(float x) {
#ifdef HAVE_PL16SWAP
  auto rr = __builtin_amdgcn_permlane16_swap(__float_as_int(x), __float_as_int(x),
                                             false, false);
  return __int_as_float((int)rr[0]) + __int_as_float((int)rr[1]);
#else
  float a = x, b = x, r;
  asm("s_nop 1\n\t"
      "v_permlane16_swap_b32 %1, %2\n\t"
      "s_nop 1\n\t"
      "v_add_f32 %0, %1, %2"
      : "=v"(r), "+v"(a), "+v"(b));
  return r;
#endif
}

// Sum over each 32-lane group; result broadcast to all lanes of the group.
__device__ __forceinline__ float allsum32(float x) {
  x = dpp_add<0xB1>(x);    // quad_perm xor 1
  x = dpp_add<0x4E>(x);    // quad_perm xor 2
  x = dpp_add<0x141>(x);   // row_half_mirror: xor 7
  x = dpp_add<0x140>(x);   // row_mirror: xor 15
  return xor16_add(x);     // xor 16 (VALU, no LDS pipe)
}

// 32 lanes per (graph b, template t) pair, 2 pairs per 64-thread single-wave
// block (empirically the optimal decomposition; r1/r2 showed 64-lane and
// 16-lane variants both lose). Lane owns 4 rows r = sub + 32*c.
__global__ __launch_bounds__(64, 2)
void tgw_kernel(const int* __restrict__ ei,
                const float* __restrict__ tadj,
                const float* __restrict__ q0g,
                float* __restrict__ out,
                int E, int ne) {
  const int lane = threadIdx.x;
  const int p    = lane >> 5;        // pair slot 0/1
  const int sub  = lane & 31;
  const int b    = blockIdx.x >> 3;
  const int t0   = (blockIdx.x & 7) * 2;   // templates t0, t0+1

  __shared__ __align__(16) unsigned adj[NN][4];    // 2 KB
  __shared__ __align__(16) float Pls[2][NN][PSTR]; // 12 KB
  __shared__ __align__(16) v2f C2T[2][NM][6];      // SC2*C2, [m][jpair]
  __shared__ float q0s[2][NM];

  // ---- stage ----
  for (int i = lane; i < NN * 4; i += 64) (&adj[0][0])[i] = 0u;
  // C2T[tt][m][jp] = SC2 * { C2[2jp][m], C2[2jp+1][m] }  (transposed pairs)
  for (int i = lane; i < 2 * NM * 5; i += 64) {
    int tt = i / 50, r = i % 50, m = r / 5, jp = r % 5;
    const float* bp = tadj + (t0 + tt) * NM * NM + m;
    C2T[tt][m][jp] = (v2f){bp[(2 * jp) * NM], bp[(2 * jp + 1) * NM]} * SC2;
  }
  if (lane < 2 * NM) q0s[lane / NM][lane % NM] = q0g[t0 * NM + lane];
  __syncthreads();

  // symmetric 0/1 adjacency from the edge list (dups/self-loops harmless)
  const int* srcp = ei;
  const int* dstp = ei + E;
  const int ebase = b * ne;
  for (int e = lane; e < ne; e += 64) {
    int s = srcp[ebase + e] & (NN - 1);
    int d = dstp[ebase + e] & (NN - 1);
    atomicOr(&adj[s][d >> 5], 1u << (d & 31));
    atomicOr(&adj[d][s >> 5], 1u << (s & 31));
  }
  __syncthreads();

  // ---- per-pair constants ----
  float qv[NM];
  {
    float mx = q0s[p][0];
    #pragma unroll
    for (int j = 1; j < NM; ++j) mx = fmaxf(mx, q0s[p][j]);
    float s = 0.f;
    #pragma unroll
    for (int j = 0; j < NM; ++j) { qv[j] = __expf(q0s[p][j] - mx); s += qv[j]; }
    float inv = __builtin_amdgcn_rcpf(s);
    #pragma unroll
    for (int j = 0; j < NM; ++j) qv[j] *= inv;
  }
  // q2d = q*128: pw=1/128 folded out of the Sinkhorn inner loop
  // (u' = rcp(rowsum)). Exact power-of-2 scalings. Harness-verified r1-r3.
  v2f q2d[5];
  #pragma unroll
  for (int jp = 0; jp < 5; ++jp)
    q2d[jp] = (v2f){qv[2 * jp] * 128.f, qv[2 * jp + 1] * 128.f};

  // fq2[jp] = -SC1 * f2q[jpair]; f2q[j] = sum_m C2[j][m]^2 q[m]
  // C2 = C2T/SC2 => factor -SC1/SC2^2 = -1/(4*SC1)
  // qC2T[jp] = sum_m q[m] * C2T[m][jp]   (for the o==0 analytic cost)
  v2f fq2[5], qC2T[5];
  {
    #pragma unroll
    for (int jp = 0; jp < 5; ++jp) { fq2[jp] = (v2f){0.f, 0.f}; qC2T[jp] = (v2f){0.f, 0.f}; }
    #pragma unroll
    for (int m = 0; m < NM; ++m) {
      v2f qb = bc2(qv[m]);
      #pragma unroll
      for (int jp = 0; jp < 5; ++jp) {
        v2f c = C2T[p][m][jp];
        fq2[jp]  = pkfma(c * c, qb, fq2[jp]);
        qC2T[jp] = pkfma(c, qb, qC2T[jp]);
      }
    }
    const float f = -1.0f / (4.0f * SC1);
    #pragma unroll
    for (int jp = 0; jp < 5; ++jp) fq2[jp] *= f;
  }

  const float pw = 1.0f / 128.0f;
  float f1p[4], m1f1[4];
  #pragma unroll
  for (int c = 0; c < 4; ++c) {
    uint4 mm = *(const uint4*)&adj[sub + 32 * c][0];
    u64 m0 = mm.x | ((u64)mm.y << 32), m1 = mm.z | ((u64)mm.w << 32);
    f1p[c]  = (float)(__popcll(m0) + __popcll(m1)) * pw;   // C1*C1 == C1
    m1f1[c] = -SC1 * f1p[c];
  }

  const float* Pbase = &Pls[p][0][0];

  // sparse gather S = (C1 @ P)[row r], 2-deep software-pipelined:
  // per body: issue neighbor k0's 3 loads, issue k1's 3 loads, THEN accumulate
  // k0 (compiler waits lgkmcnt(3): k0's wait overlaps k1's flight), then k1.
  // Same serial per-row walk as baseline (no joint-mask iteration inflation --
  // the r0/r3 mistake), same per-lane ascending-k order.
  auto gatherRow = [&](int r, v2f* S2) {
    uint4 mm = *(const uint4*)&adj[r][0];
    u64 m0 = mm.x | ((u64)mm.y << 32), m1 = mm.z | ((u64)mm.w << 32);
    #pragma unroll
    for (int h = 0; h < 5; ++h) S2[h] = (v2f){0.f, 0.f};
    while (m0) {
      int k0 = (int)__builtin_ctzll(m0); m0 &= m0 - 1;
      const float* r0 = Pbase + k0 * PSTR;
      v4f A0 = *(const v4f*)r0;
      v4f B0 = *(const v4f*)(r0 + 4);
      v2f C0 = *(const v2f*)(r0 + 8);
      if (m0) {
        int k1 = (int)__builtin_ctzll(m0); m0 &= m0 - 1;
        const float* r1 = Pbase + k1 * PSTR;
        v4f A1 = *(const v4f*)r1;
        v4f B1 = *(const v4f*)(r1 + 4);
        v2f C1 = *(const v2f*)(r1 + 8);
        S2[0] += A0.xy; S2[1] += A0.zw; S2[2] += B0.xy; S2[3] += B0.zw; S2[4] += C0;
        S2[0] += A1.xy; S2[1] += A1.zw; S2[2] += B1.xy; S2[3] += B1.zw; S2[4] += C1;
      } else {
        S2[0] += A0.xy; S2[1] += A0.zw; S2[2] += B0.xy; S2[3] += B0.zw; S2[4] += C0;
      }
    }
    while (m1) {
      int k0 = 64 + (int)__builtin_ctzll(m1); m1 &= m1 - 1;
      const float* r0 = Pbase + k0 * PSTR;
      v4f A0 = *(const v4f*)r0;
      v4f B0 = *(const v4f*)(r0 + 4);
      v2f C0 = *(const v2f*)(r0 + 8);
      if (m1) {
        int k1 = 64 + (int)__builtin_ctzll(m1); m1 &= m1 - 1;
        const float* r1 = Pbase + k1 * PSTR;
        v4f A1 = *(const v4f*)r1;
        v4f B1 = *(const v4f*)(r1 + 4);
        v2f C1 = *(const v2f*)(r1 + 8);
        S2[0] += A0.xy; S2[1] += A0.zw; S2[2] += B0.xy; S2[3] += B0.zw; S2[4] += C0;
        S2[0] += A1.xy; S2[1] += A1.zw; S2[2] += B1.xy; S2[3] += B1.zw; S2[4] += C1;
      } else {
        S2[0] += A0.xy; S2[1] += A0.zw; S2[2] += B0.xy; S2[3] += B0.zw; S2[4] += C0;
      }
    }
  };

  // arg2[c][jp] = -SC1*tens (packed over jpairs), from scalar S[m] per row
  auto costFromS = [&](float Sm[4][NM], v2f arg2[4][5]) {
    #pragma unroll
    for (int c = 0; c < 4; ++c) {
      #pragma unroll
      for (int jp = 0; jp < 5; ++jp) arg2[c][jp] = fq2[jp] + bc2(m1f1[c]);
    }
    #pragma unroll
    for (int m = 0; m < NM; ++m) {
      v4f X = *(const v4f*)&C2T[p][m][0];   // jp 0,1
      v4f Y = *(const v4f*)&C2T[p][m][2];   // jp 2,3
      v2f Z = *(const v2f*)&C2T[p][m][4];   // jp 4
      #pragma unroll
      for (int c = 0; c < 4; ++c) {
        v2f sb = bc2(Sm[c][m]);
        arg2[c][0] = pkfma(sb, X.xy, arg2[c][0]);
        arg2[c][1] = pkfma(sb, X.zw, arg2[c][1]);
        arg2[c][2] = pkfma(sb, Y.xy, arg2[c][2]);
        arg2[c][3] = pkfma(sb, Y.zw, arg2[c][3]);
        arg2[c][4] = pkfma(sb, Z,    arg2[c][4]);
      }
    }
  };

  v2f K2[4][5], v2[5], arg2[4][5];
  float uu[4];

  for (int o = 0; o < OUTER_IT; ++o) {
    // ---- cost -> arg2 -> K = exp2(arg) ----
    if (o == 0) {
      // P0 = p q^T => S[c][m] = f1p[c]*q[m] => sum_m S C2T = f1p[c]*qC2T
      #pragma unroll
      for (int c = 0; c < 4; ++c) {
        v2f fb = bc2(f1p[c]);
        v2f ob = bc2(m1f1[c]);
        #pragma unroll
        for (int jp = 0; jp < 5; ++jp)
          arg2[c][jp] = pkfma(fb, qC2T[jp], fq2[jp] + ob);
      }
    } else {
      float Sm[4][NM];
      #pragma unroll
      for (int c = 0; c < 4; ++c) {
        v2f S2[5];
        gatherRow(sub + 32 * c, S2);
        #pragma unroll
        for (int h = 0; h < 5; ++h) { Sm[c][2 * h] = S2[h].x; Sm[c][2 * h + 1] = S2[h].y; }
      }
      costFromS(Sm, arg2);
    }
    #pragma unroll
    for (int c = 0; c < 4; ++c)
      #pragma unroll
      for (int jp = 0; jp < 5; ++jp)
        K2[c][jp] = (v2f){exp2f(arg2[c][jp].x), exp2f(arg2[c][jp].y)};

    // ---- Sinkhorn (v starts at ones; pw folded: uu = rcp(rowsum)) ----
    #pragma unroll
    for (int jp = 0; jp < 5; ++jp) v2[jp] = (v2f){1.f, 1.f};
    for (int it = 0; it < SINK_IT; ++it) {
      #pragma unroll
      for (int c = 0; c < 4; ++c) {
        v2f d2 = K2[c][0] * v2[0];
        d2 = pkfma(K2[c][1], v2[1], d2);
        d2 = pkfma(K2[c][2], v2[2], d2);
        d2 = pkfma(K2[c][3], v2[3], d2);
        d2 = pkfma(K2[c][4], v2[4], d2);
        uu[c] = __builtin_amdgcn_rcpf(d2.x + d2.y);
      }
      #pragma unroll
      for (int jp = 0; jp < 5; ++jp) {
        v2f w2 = K2[0][jp] * bc2(uu[0]);
        w2 = pkfma(K2[1][jp], bc2(uu[1]), w2);
        w2 = pkfma(K2[2][jp], bc2(uu[2]), w2);
        w2 = pkfma(K2[3][jp], bc2(uu[3]), w2);
        float cx = allsum32(w2.x);
        float cy = allsum32(w2.y);
        v2[jp] = (v2f){q2d[jp].x * __builtin_amdgcn_rcpf(cx),
                       q2d[jp].y * __builtin_amdgcn_rcpf(cy)};
      }
    }

    // ---- P = diag(u) K diag(v) -> LDS (re-apply pw once here) ----
    __syncthreads();   // single-wave block: just drains LDS ops, ~free
    #pragma unroll
    for (int c = 0; c < 4; ++c) {
      v2f ub = bc2(uu[c] * pw);   // exact *2^-7
      v2f x0 = K2[c][0] * ub * v2[0];
      v2f x1 = K2[c][1] * ub * v2[1];
      v2f x2 = K2[c][2] * ub * v2[2];
      v2f x3 = K2[c][3] * ub * v2[3];
      v2f x4 = K2[c][4] * ub * v2[4];
      float* row = &Pls[p][sub + 32 * c][0];
      *(v4f*)row       = (v4f){x0.x, x0.y, x1.x, x1.y};
      *(v4f*)(row + 4) = (v4f){x2.x, x2.y, x3.x, x3.y};
      *(v2f*)(row + 8) = x4;
    }
    __syncthreads();
  }

  // ---- GW = sum_ij tens(P)_ij * P_ij,  tens = arg * (-1/SC1) ----
  float acc = 0.f;
  {
    float Sm[4][NM];
    #pragma unroll
    for (int c = 0; c < 4; ++c) {
      v2f S2[5];
      gatherRow(sub + 32 * c, S2);
      #pragma unroll
      for (int h = 0; h < 5; ++h) { Sm[c][2 * h] = S2[h].x; Sm[c][2 * h + 1] = S2[h].y; }
    }
    costFromS(Sm, arg2);
    const v2f nf = bc2(-1.0f / SC1);
    v2f acc2 = (v2f){0.f, 0.f};
    #pragma unroll
    for (int c = 0; c < 4; ++c) {
      v2f ub = bc2(uu[c] * pw);
      #pragma unroll
      for (int jp = 0; jp < 5; ++jp) {
        v2f Pv = K2[c][jp] * ub * v2[jp];
        acc2 = pkfma(arg2[c][jp] * nf, Pv, acc2);
      }
    }
    acc = acc2.x + acc2.y;
  }
  float total = allsum32(acc);
  if (sub == 0) out[b * NT + t0 + p] = total;
}

extern "C" void kernel_launch(void* const* d_in, const int* in_sizes, int n_in,
                              void* d_out, int out_size, void* d_ws, size_t ws_size,
                              hipStream_t stream) {
  // inputs: 0 x(f32, unused) 1 edge_index(int32) 2 batch(int32, unused)
  //         3 tplt_adjacencies(f32) 4 tplt_features(f32, unused) 5 q0(f32)
  const int* ei   = (const int*)d_in[1];
  const float* c2 = (const float*)d_in[3];
  const float* q0 = (const float*)d_in[5];
  float* out      = (float*)d_out;
  const int E  = in_sizes[1] / 2;
  const int ne = E / NGRAPH;
  tgw_kernel<<<dim3(NGRAPH * 8), dim3(64), 0, stream>>>(ei, c2, q0, out, E, ne);
}